// Round 4
// baseline (161.104 us; speedup 1.0000x reference)
//
#include <hip/hip_runtime.h>
#include <hip/hip_fp16.h>

typedef float v2f __attribute__((ext_vector_type(2)));
typedef float v4f __attribute__((ext_vector_type(4)));
typedef int   v4i __attribute__((ext_vector_type(4)));

__device__ __constant__ float GC[16][4] = {
  {0,0,0,0},{0,0,0,1},{0,1,0,-1},{0,1,0,0},
  {0,0,1,-1},{0,0,1,0},{0,1,1,-2},{0,1,1,-1},
  {1,-1,-1,1},{1,-1,-1,2},{1,0,-1,0},{1,0,-1,1},
  {1,-1,0,0},{1,-1,0,1},{1,0,0,-1},{1,0,0,0}};

// ---- packed fp32 helpers (V_PK_FMA/MUL exist on gfx950) ----
__device__ __forceinline__ v2f pk_mul(v2f a, v2f b) {
  v2f d;
  asm("v_pk_mul_f32 %0, %1, %2" : "=v"(d) : "v"(a), "v"(b));
  return d;
}
// r = w0 + w1*a + w2*b + w3*(a*b), per half; w01=(w0,w1) pair, w23=(w2,w3).
__device__ __forceinline__ v2f gate2pk(v2f a, v2f b, v2f w01, v2f w23) {
  v2f t = pk_mul(a, b);
  v2f d;
  asm("v_pk_fma_f32 %0, %1, %2, %2 op_sel:[0,1,0] op_sel_hi:[1,1,0]"
      : "=v"(d) : "v"(a), "v"(w01));
  asm("v_pk_fma_f32 %0, %1, %2, %0 op_sel:[0,0,0] op_sel_hi:[1,0,1]"
      : "+v"(d) : "v"(b), "v"(w23));
  asm("v_pk_fma_f32 %0, %1, %2, %0 op_sel:[0,1,0] op_sel_hi:[1,1,1]"
      : "+v"(d) : "v"(t), "v"(w23));
  return d;
}

__device__ __forceinline__ void mix_one(const float* lp, float* op) {
  // logits are 0.01*N(0,1) (+5 on slot 3): exp() safe without max-shift
  float e[16];
  float s = 0.f;
  #pragma unroll
  for (int i = 0; i < 16; ++i) { e[i] = __expf(lp[i]); s += e[i]; }
  float inv = 1.0f / s;
  float w0 = 0.f, w1 = 0.f, w2 = 0.f, w3 = 0.f;
  #pragma unroll
  for (int i = 0; i < 16; ++i) {
    float p = e[i] * inv;
    w0 = fmaf(p, GC[i][0], w0);
    w1 = fmaf(p, GC[i][1], w1);
    w2 = fmaf(p, GC[i][2], w2);
    w3 = fmaf(p, GC[i][3], w3);
  }
  op[0] = w0; op[1] = w1; op[2] = w2; op[3] = w3;
}

struct PrepArgs {
  const float* logits[7];
  float* outm[7];
  const int* cidx[4];
  int* offt[4];
};

// gid 0..83551: weight softmax-mix -> 4 coefs/row.
// gid 83552..85247: decode leaf indices into direct LDS element offsets
// (relative to a zero-halo'd [C][H+2][W+2] input buffer).
__global__ __launch_bounds__(256) void prep_k(PrepArgs A) {
  int gid = blockIdx.x * 256 + threadIdx.x;
  if (gid < 83552) {
    const int n[7] = {224, 896, 3584, 7168, 40960, 20480, 10240};
    int g = gid, seg = 0;
    while (seg < 6 && g >= n[seg]) { g -= n[seg]; ++seg; }
    mix_one(A.logits[seg] + (size_t)g * 16, A.outm[seg] + (size_t)g * 4);
  } else if (gid < 85248) {
    int r = gid - 83552;
    int L, rr, H;
    if (r < 32)       { L = 0; rr = r;       H = 32; }
    else if (r < 160) { L = 1; rr = r - 32;  H = 16; }
    else if (r < 672) { L = 2; rr = r - 160; H = 8;  }
    else              { L = 3; rr = r - 672; H = 4;  }
    const int* ci = A.cidx[L] + rr * 8;
    int* oo = A.offt[L] + rr * 8;
    int W2 = H + 2;
    #pragma unroll
    for (int l = 0; l < 8; ++l) {
      int idx = ci[l];
      int c  = idx / 9;
      int k  = idx - 9 * c;
      int di = k / 3 - 1;
      int dj = k - 3 * (k / 3) - 1;
      oo[l] = (c * (H + 2) + 1 + di) * W2 + 1 + dj;
    }
  }
}

struct MegaArgs {
  const float* x;
  const float* mc[4];    // mixed conv weights (OC x 28)
  const int*   offt[4];  // decoded leaf offsets (OC x 8)
  const int*   la[3];
  const int*   lb[3];
  const float* mlw[3];   // mixed logic weights (N x 4)
  float* out;
};

extern __shared__ char S[];

// One conv+or_pool layer, input/output in LDS (zero halo -> no bounds checks).
// Thread -> output pixel (lane-varying), channel loop (wave-uniform for
// conv1/2 -> s_loads of offsets+weights). pk packs the 2x2 pool window.
template<int OH, int OW, int LOGOW, int IW2, int PIXCNT, int LOGPIX,
         int NCH, int ITERS, bool UNI, bool HALO>
__device__ __forceinline__ void conv_stage(
    const float* in, float* outb,
    const int* __restrict__ offt, const float* __restrict__ mtab, int tid) {
  int pix = tid & (PIXCNT - 1);
  int ch0 = tid >> LOGPIX;
  int pw  = pix & (OW - 1);
  int ph  = pix >> LOGOW;
  int pixbase = (2 * ph) * IW2 + 2 * pw;
  #pragma unroll 2
  for (int it = 0; it < ITERS; ++it) {
    int ch = ch0 + NCH * it;
    if (UNI) ch = __builtin_amdgcn_readfirstlane(ch);
    const int* ot = offt + ch * 8;
    const float* mt = mtab + ch * 28;
    v4f g0 = *(const v4f*)(mt +  0);
    v4f g1 = *(const v4f*)(mt +  4);
    v4f g2 = *(const v4f*)(mt +  8);
    v4f g3 = *(const v4f*)(mt + 12);
    v4f g4 = *(const v4f*)(mt + 16);
    v4f g5 = *(const v4f*)(mt + 20);
    v4f g6 = *(const v4f*)(mt + 24);
    v2f v01[8], v23[8];
    #pragma unroll
    for (int l = 0; l < 8; ++l) {
      int a0 = ot[l] + pixbase;
      v2f t0; t0.x = in[a0];       t0.y = in[a0 + 1];
      v2f t1; t1.x = in[a0 + IW2]; t1.y = in[a0 + IW2 + 1];
      v01[l] = t0; v23[l] = t1;
    }
    v2f u0 = gate2pk(v01[0], v01[1], g0.xy, g0.zw);
    v2f u1 = gate2pk(v01[2], v01[3], g1.xy, g1.zw);
    v2f u2 = gate2pk(v01[4], v01[5], g2.xy, g2.zw);
    v2f u3 = gate2pk(v01[6], v01[7], g3.xy, g3.zw);
    v2f s0 = gate2pk(u0, u1, g4.xy, g4.zw);
    v2f s1 = gate2pk(u2, u3, g5.xy, g5.zw);
    v2f r0 = gate2pk(s0, s1, g6.xy, g6.zw);
    u0 = gate2pk(v23[0], v23[1], g0.xy, g0.zw);
    u1 = gate2pk(v23[2], v23[3], g1.xy, g1.zw);
    u2 = gate2pk(v23[4], v23[5], g2.xy, g2.zw);
    u3 = gate2pk(v23[6], v23[7], g3.xy, g3.zw);
    s0 = gate2pk(u0, u1, g4.xy, g4.zw);
    s1 = gate2pk(u2, u3, g5.xy, g5.zw);
    v2f r1 = gate2pk(s0, s1, g6.xy, g6.zw);
    float res = fmaxf(fmaxf(r0.x, r0.y), fmaxf(r1.x, r1.y));
    if (HALO)
      outb[ch * (OH + 2) * (OW + 2) + (1 + ph) * (OW + 2) + 1 + pw] = res;
    else
      outb[ch * (OH * OW) + pix] = res;
  }
}

// LDS layout (bytes):
//  binb [9][34][34] f32   @ 0       (41616)
//  buf1 [32][18][18] f32  @ 53248   (41472)  ends 94720
//  buf2 [128][10][10] f32 @ 0       (51200)
//  buf3 [512][6][6] f32   @ 53248   (73728)  ends 126976
//  h4   [4096] f32        @ 0       (16384)
//  g1h  [40960] f16       @ 16384   (81920)  ends 98304
//  g2h  [20480] f16       @ 98304   (40960)  ends 139264
//  lsum [10] f32          @ 139264
__global__ __launch_bounds__(512, 2) void mega_k(MegaArgs A) {
  int tid = threadIdx.x;
  int b = blockIdx.x;
  float* binb = (float*)(S);
  float* buf1 = (float*)(S + 53248);
  float* buf2 = (float*)(S);
  float* buf3 = (float*)(S + 53248);
  float* h4   = (float*)(S);
  __half* g1h = (__half*)(S + 16384);
  __half* g2h = (__half*)(S + 98304);
  float* lsum = (float*)(S + 139264);

  // ---- binarize into zero-halo'd binb ----
  for (int i = tid; i < 10404; i += 512) binb[i] = 0.f;
  if (tid < 10) lsum[tid] = 0.f;
  __syncthreads();
  const float* xb = A.x + (size_t)b * 3072;
  #pragma unroll
  for (int i = 0; i < 6; ++i) {
    int idx = tid + 512 * i;
    float v = xb[idx];
    int rgb = idx >> 10;
    int rem = idx & 1023;
    int y = rem >> 5, xx = rem & 31;
    int base = (1 + y) * 34 + 1 + xx;
    binb[(0 + rgb) * 1156 + base] = v > 0.25f ? 1.f : 0.f;
    binb[(3 + rgb) * 1156 + base] = v > 0.50f ? 1.f : 0.f;
    binb[(6 + rgb) * 1156 + base] = v > 0.75f ? 1.f : 0.f;
  }
  __syncthreads();

  // ---- conv1: binb -> buf1 ----
  for (int i = tid; i < 10368; i += 512) buf1[i] = 0.f;
  __syncthreads();
  conv_stage<16,16,4,34,256,8,2,16,true,true>(binb, buf1, A.offt[0], A.mc[0], tid);
  __syncthreads();
  // ---- conv2: buf1 -> buf2 ----
  for (int i = tid; i < 12800; i += 512) buf2[i] = 0.f;
  __syncthreads();
  conv_stage<8,8,3,18,64,6,8,16,true,true>(buf1, buf2, A.offt[1], A.mc[1], tid);
  __syncthreads();
  // ---- conv3: buf2 -> buf3 ----
  for (int i = tid; i < 18432; i += 512) buf3[i] = 0.f;
  __syncthreads();
  conv_stage<4,4,2,10,16,4,32,16,false,true>(buf2, buf3, A.offt[2], A.mc[2], tid);
  __syncthreads();
  // ---- conv4: buf3 -> h4 (flat, no halo) ----
  conv_stage<2,2,1,6,4,2,128,8,false,false>(buf3, h4, A.offt[3], A.mc[3], tid);
  __syncthreads();

  // ---- logic1: h4(f32) -> g1h(f16), 40960 rows ----
  {
    const v4i* a4 = (const v4i*)A.la[0];
    const v4i* b4 = (const v4i*)A.lb[0];
    const v4f* w4 = (const v4f*)A.mlw[0];
    #pragma unroll 2
    for (int g = 0; g < 20; ++g) {
      int q = tid + 512 * g;
      v4i ai = a4[q], bi = b4[q];
      #pragma unroll
      for (int i = 0; i < 4; ++i) {
        v4f w = w4[4 * q + i];
        float a = h4[ai[i]], bb = h4[bi[i]];
        g1h[4 * q + i] = __float2half(fmaf(w.w, a * bb, fmaf(w.z, bb, fmaf(w.y, a, w.x))));
      }
    }
  }
  __syncthreads();
  // ---- logic2: g1h -> g2h, 20480 rows ----
  {
    const v4i* a4 = (const v4i*)A.la[1];
    const v4i* b4 = (const v4i*)A.lb[1];
    const v4f* w4 = (const v4f*)A.mlw[1];
    #pragma unroll 2
    for (int g = 0; g < 10; ++g) {
      int q = tid + 512 * g;
      v4i ai = a4[q], bi = b4[q];
      #pragma unroll
      for (int i = 0; i < 4; ++i) {
        v4f w = w4[4 * q + i];
        float a = __half2float(g1h[ai[i]]), bb = __half2float(g2h == 0 ? g1h[bi[i]] : g1h[bi[i]]);
        g2h[4 * q + i] = __float2half(fmaf(w.w, a * bb, fmaf(w.z, bb, fmaf(w.y, a, w.x))));
      }
    }
  }
  __syncthreads();
  // ---- logic3 + group-sum: g2h -> per-class sums ----
  // j = 4*(tid+512*g); each wave's 256 consecutive j's lie in one class
  // (256 | 1024) -> wave shuffle-reduce, lane0 does one LDS atomic.
  {
    const v4i* a4 = (const v4i*)A.la[2];
    const v4i* b4 = (const v4i*)A.lb[2];
    const v4f* w4 = (const v4f*)A.mlw[2];
    int wv = tid >> 6, lane = tid & 63;
    #pragma unroll
    for (int g = 0; g < 5; ++g) {
      int q = tid + 512 * g;
      v4i ai = a4[q], bi = b4[q];
      float s = 0.f;
      #pragma unroll
      for (int i = 0; i < 4; ++i) {
        v4f w = w4[4 * q + i];
        float a = __half2float(g2h[ai[i]]), bb = __half2float(g2h[bi[i]]);
        s += fmaf(w.w, a * bb, fmaf(w.z, bb, fmaf(w.y, a, w.x)));
      }
      #pragma unroll
      for (int m = 1; m < 64; m <<= 1) s += __shfl_xor(s, m);
      if (lane == 0) atomicAdd(&lsum[(wv + 8 * g) >> 2], s);
    }
  }
  __syncthreads();
  if (tid < 10) A.out[b * 10 + tid] = lsum[tid] * 0.01f;
}

extern "C" void kernel_launch(void* const* d_in, const int* in_sizes, int n_in,
                              void* d_out, int out_size, void* d_ws, size_t ws_size,
                              hipStream_t stream) {
  const float* x   = (const float*)d_in[0];
  const int*   c1i = (const int*)d_in[1];
  const float* c1w = (const float*)d_in[2];
  const int*   c2i = (const int*)d_in[3];
  const float* c2w = (const float*)d_in[4];
  const int*   c3i = (const int*)d_in[5];
  const float* c3w = (const float*)d_in[6];
  const int*   c4i = (const int*)d_in[7];
  const float* c4w = (const float*)d_in[8];
  const int*   l1a = (const int*)d_in[9];
  const int*   l1b = (const int*)d_in[10];
  const float* l1w = (const float*)d_in[11];
  const int*   l2a = (const int*)d_in[12];
  const int*   l2b = (const int*)d_in[13];
  const float* l2w = (const float*)d_in[14];
  const int*   l3a = (const int*)d_in[15];
  const int*   l3b = (const int*)d_in[16];
  const float* l3w = (const float*)d_in[17];

  float* ws = (float*)d_ws;
  float* mc1 = ws;               // 224*4
  float* mc2 = mc1 + 896;        // 896*4
  float* mc3 = mc2 + 3584;       // 3584*4
  float* mc4 = mc3 + 14336;      // 7168*4
  float* ml1 = mc4 + 28672;      // 40960*4
  float* ml2 = ml1 + 163840;     // 20480*4
  float* ml3 = ml2 + 81920;      // 10240*4
  int* off1 = (int*)(ml3 + 40960);   // 32*8
  int* off2 = off1 + 256;            // 128*8
  int* off3 = off2 + 1024;           // 512*8
  int* off4 = off3 + 4096;           // 1024*8

  PrepArgs P;
  P.logits[0] = c1w; P.outm[0] = mc1;
  P.logits[1] = c2w; P.outm[1] = mc2;
  P.logits[2] = c3w; P.outm[2] = mc3;
  P.logits[3] = c4w; P.outm[3] = mc4;
  P.logits[4] = l1w; P.outm[4] = ml1;
  P.logits[5] = l2w; P.outm[5] = ml2;
  P.logits[6] = l3w; P.outm[6] = ml3;
  P.cidx[0] = c1i; P.offt[0] = off1;
  P.cidx[1] = c2i; P.offt[1] = off2;
  P.cidx[2] = c3i; P.offt[2] = off3;
  P.cidx[3] = c4i; P.offt[3] = off4;
  prep_k<<<333, 256, 0, stream>>>(P);

  MegaArgs M;
  M.x = x;
  M.mc[0] = mc1; M.mc[1] = mc2; M.mc[2] = mc3; M.mc[3] = mc4;
  M.offt[0] = off1; M.offt[1] = off2; M.offt[2] = off3; M.offt[3] = off4;
  M.la[0] = l1a; M.lb[0] = l1b; M.mlw[0] = ml1;
  M.la[1] = l2a; M.lb[1] = l2b; M.mlw[1] = ml2;
  M.la[2] = l3a; M.lb[2] = l3b; M.mlw[2] = ml3;
  M.out = (float*)d_out;

  static bool attr_set = false;
  if (!attr_set) {
    hipFuncSetAttribute((const void*)mega_k,
                        hipFuncAttributeMaxDynamicSharedMemorySize, 139328);
    attr_set = true;
  }
  mega_k<<<128, 512, 139328, stream>>>(M);
}

// Round 5
// 157.424 us; speedup vs baseline: 1.0234x; 1.0234x over previous
//
#include <hip/hip_runtime.h>
#include <hip/hip_fp16.h>

typedef float v2f __attribute__((ext_vector_type(2)));
typedef float v4f __attribute__((ext_vector_type(4)));
typedef int   v4i __attribute__((ext_vector_type(4)));

__device__ __constant__ float GC[16][4] = {
  {0,0,0,0},{0,0,0,1},{0,1,0,-1},{0,1,0,0},
  {0,0,1,-1},{0,0,1,0},{0,1,1,-2},{0,1,1,-1},
  {1,-1,-1,1},{1,-1,-1,2},{1,0,-1,0},{1,0,-1,1},
  {1,-1,0,0},{1,-1,0,1},{1,0,0,-1},{1,0,0,0}};

// ---- packed fp32 helpers (V_PK_FMA/MUL exist on gfx950) ----
__device__ __forceinline__ v2f pk_mul(v2f a, v2f b) {
  v2f d;
  asm("v_pk_mul_f32 %0, %1, %2" : "=v"(d) : "v"(a), "v"(b));
  return d;
}
// r = w0 + w1*a + w2*b + w3*(a*b), per half; w01=(w0,w1) pair, w23=(w2,w3).
__device__ __forceinline__ v2f gate2pk(v2f a, v2f b, v2f w01, v2f w23) {
  v2f t = pk_mul(a, b);
  v2f d;
  asm("v_pk_fma_f32 %0, %1, %2, %2 op_sel:[0,1,0] op_sel_hi:[1,1,0]"
      : "=v"(d) : "v"(a), "v"(w01));
  asm("v_pk_fma_f32 %0, %1, %2, %0 op_sel:[0,0,0] op_sel_hi:[1,0,1]"
      : "+v"(d) : "v"(b), "v"(w23));
  asm("v_pk_fma_f32 %0, %1, %2, %0 op_sel:[0,1,0] op_sel_hi:[1,1,1]"
      : "+v"(d) : "v"(t), "v"(w23));
  return d;
}

__device__ __forceinline__ void mix_one(const float* lp, float* op) {
  // logits are 0.01*N(0,1) (+5 on slot 3): exp() safe without max-shift
  float e[16];
  float s = 0.f;
  #pragma unroll
  for (int i = 0; i < 16; ++i) { e[i] = __expf(lp[i]); s += e[i]; }
  float inv = 1.0f / s;
  float w0 = 0.f, w1 = 0.f, w2 = 0.f, w3 = 0.f;
  #pragma unroll
  for (int i = 0; i < 16; ++i) {
    float p = e[i] * inv;
    w0 = fmaf(p, GC[i][0], w0);
    w1 = fmaf(p, GC[i][1], w1);
    w2 = fmaf(p, GC[i][2], w2);
    w3 = fmaf(p, GC[i][3], w3);
  }
  op[0] = w0; op[1] = w1; op[2] = w2; op[3] = w3;
}

struct PrepArgs {
  const float* logits[7];
  float* outm[7];
  const int* cidx[4];
  int* offt[4];
};

// gid 0..83551: weight softmax-mix -> 4 coefs/row.
// gid 83552..85247: decode leaf indices into LDS element offsets relative to a
// zero-halo'd, row-swizzled [C][H+2][W+3] buffer. Swizzle: element (y,x) is
// stored at x + ((y>>1)&1). off = c*CS + yl*W2P + 1+dj (yl = 1+di), with
// bit28 = (yl>>1)&1 and bit29 = ((yl+1)>>1)&1 (swizzle parity constants for
// the top/bottom row reads; full bit = ph&1 XOR const).
__global__ __launch_bounds__(256) void prep_k(PrepArgs A) {
  int gid = blockIdx.x * 256 + threadIdx.x;
  if (gid < 83552) {
    const int n[7] = {224, 896, 3584, 7168, 40960, 20480, 10240};
    int g = gid, seg = 0;
    while (seg < 6 && g >= n[seg]) { g -= n[seg]; ++seg; }
    mix_one(A.logits[seg] + (size_t)g * 16, A.outm[seg] + (size_t)g * 4);
  } else if (gid < 85248) {
    int r = gid - 83552;
    int L, rr;
    if (r < 32)       { L = 0; rr = r;       }
    else if (r < 160) { L = 1; rr = r - 32;  }
    else if (r < 672) { L = 2; rr = r - 160; }
    else              { L = 3; rr = r - 672; }
    const int W2Pt[4] = {35, 19, 11, 6};
    const int CSt[4]  = {1190, 342, 110, 36};
    const int swzt[4] = {1, 1, 1, 0};
    int W2P = W2Pt[L], CS = CSt[L], swz = swzt[L];
    const int* ci = A.cidx[L] + rr * 8;
    int* oo = A.offt[L] + rr * 8;
    #pragma unroll
    for (int l = 0; l < 8; ++l) {
      int idx = ci[l];
      int c  = idx / 9;
      int k  = idx - 9 * c;
      int di = k / 3 - 1;
      int dj = k - 3 * (k / 3) - 1;
      int yl = 1 + di;                      // 0..2
      int off = c * CS + yl * W2P + 1 + dj;
      if (swz)
        off |= (((yl >> 1) & 1) << 28) | ((((yl + 1) >> 1) & 1) << 29);
      oo[l] = off;
    }
  }
}

struct MegaArgs {
  const float* x;
  const float* mc[4];    // mixed conv weights (OC x 28)
  const int*   offt[4];  // decoded leaf offsets (OC x 8)
  const int*   la[3];
  const int*   lb[3];
  const float* mlw[3];   // mixed logic weights (N x 4)
  float* out;
};

extern __shared__ char S[];

// One conv+or_pool layer, input/output in LDS (zero halo -> no bounds checks,
// row swizzle -> bank-conflict-free stride-2 lane access).
template<int OH, int OW, int LOGOW, int IW2P, int PIXCNT, int LOGPIX,
         int NCH, int ITERS, bool UNI, bool RSWZ, bool OHALO, int OW2P, bool OSWZ>
__device__ __forceinline__ void conv_stage(
    const float* in, float* outb,
    const int* __restrict__ offt, const float* __restrict__ mtab, int tid) {
  int pix = tid & (PIXCNT - 1);
  int ch0 = tid >> LOGPIX;
  int pw  = pix & (OW - 1);
  int ph  = pix >> LOGOW;
  int pixbase = 2 * ph * IW2P + 2 * pw;
  int ph1 = ph & 1;
  #pragma unroll 2
  for (int it = 0; it < ITERS; ++it) {
    int ch = ch0 + NCH * it;
    if (UNI) ch = __builtin_amdgcn_readfirstlane(ch);
    const int* ot = offt + ch * 8;
    const float* mt = mtab + ch * 28;
    v4f g0 = *(const v4f*)(mt +  0);
    v4f g1 = *(const v4f*)(mt +  4);
    v4f g2 = *(const v4f*)(mt +  8);
    v4f g3 = *(const v4f*)(mt + 12);
    v4f g4 = *(const v4f*)(mt + 16);
    v4f g5 = *(const v4f*)(mt + 20);
    v4f g6 = *(const v4f*)(mt + 24);
    v2f v01[8], v23[8];
    #pragma unroll
    for (int l = 0; l < 8; ++l) {
      int e = ot[l];
      int at, ab;
      if (RSWZ) {
        int off = e & 0x0FFFFFFF;
        at = off + pixbase + ((ph1 ^ (e >> 28)) & 1);
        ab = off + pixbase + IW2P + ((ph1 ^ (e >> 29)) & 1);
      } else {
        at = e + pixbase;
        ab = at + IW2P;
      }
      v2f t0; t0.x = in[at]; t0.y = in[at + 1];
      v2f t1; t1.x = in[ab]; t1.y = in[ab + 1];
      v01[l] = t0; v23[l] = t1;
    }
    v2f u0 = gate2pk(v01[0], v01[1], g0.xy, g0.zw);
    v2f u1 = gate2pk(v01[2], v01[3], g1.xy, g1.zw);
    v2f u2 = gate2pk(v01[4], v01[5], g2.xy, g2.zw);
    v2f u3 = gate2pk(v01[6], v01[7], g3.xy, g3.zw);
    v2f s0 = gate2pk(u0, u1, g4.xy, g4.zw);
    v2f s1 = gate2pk(u2, u3, g5.xy, g5.zw);
    v2f r0 = gate2pk(s0, s1, g6.xy, g6.zw);
    u0 = gate2pk(v23[0], v23[1], g0.xy, g0.zw);
    u1 = gate2pk(v23[2], v23[3], g1.xy, g1.zw);
    u2 = gate2pk(v23[4], v23[5], g2.xy, g2.zw);
    u3 = gate2pk(v23[6], v23[7], g3.xy, g3.zw);
    s0 = gate2pk(u0, u1, g4.xy, g4.zw);
    s1 = gate2pk(u2, u3, g5.xy, g5.zw);
    v2f r1 = gate2pk(s0, s1, g6.xy, g6.zw);
    float res = fmaxf(fmaxf(r0.x, r0.y), fmaxf(r1.x, r1.y));
    if (OHALO) {
      int oy = 1 + ph;
      int widx = ch * ((OH + 2) * OW2P) + oy * OW2P + 1 + pw;
      if (OSWZ) widx += (oy >> 1) & 1;
      outb[widx] = res;
    } else {
      outb[ch * (OH * OW) + pix] = res;
    }
  }
}

// LDS layout (bytes), two ping-pong regions A@0 (56320) and B@56320 (73728):
//  binb [9][34][35] f32   @ A      (42840)
//  buf1 [32][18][19] f32  @ B      (43776)
//  buf2 [128][10][11] f32 @ A      (56320)
//  buf3 [512][6][6] f32   @ B      (73728)  ends 130048
//  h4   [4096] f32        @ 0      (16384)
//  g1h  [40960] f16       @ 16384  (81920)  ends 98304
//  g2h  [20480] f16       @ 98304  (40960)  ends 139264
//  lsum [10] f32          @ 139264
__global__ __launch_bounds__(1024) void mega_k(MegaArgs A) {
  int tid = threadIdx.x;
  int b = blockIdx.x;
  float* binb = (float*)(S);
  float* buf1 = (float*)(S + 56320);
  float* buf2 = (float*)(S);
  float* buf3 = (float*)(S + 56320);
  float* h4   = (float*)(S);
  __half* g1h = (__half*)(S + 16384);
  __half* g2h = (__half*)(S + 98304);
  float* lsum = (float*)(S + 139264);

  // ---- binarize into zero-halo'd, row-swizzled binb ----
  for (int i = tid; i < 10710; i += 1024) binb[i] = 0.f;
  if (tid < 10) lsum[tid] = 0.f;
  __syncthreads();
  const float* xb = A.x + (size_t)b * 3072;
  #pragma unroll
  for (int i = 0; i < 3; ++i) {
    int idx = tid + 1024 * i;
    float v = xb[idx];
    int rgb = idx >> 10;
    int rem = idx & 1023;
    int y = rem >> 5, xx = rem & 31;
    int oy = 1 + y;
    int base = oy * 35 + 1 + xx + ((oy >> 1) & 1);
    binb[(0 + rgb) * 1190 + base] = v > 0.25f ? 1.f : 0.f;
    binb[(3 + rgb) * 1190 + base] = v > 0.50f ? 1.f : 0.f;
    binb[(6 + rgb) * 1190 + base] = v > 0.75f ? 1.f : 0.f;
  }
  __syncthreads();

  // ---- conv1: binb -> buf1 ----
  for (int i = tid; i < 10944; i += 1024) buf1[i] = 0.f;
  __syncthreads();
  conv_stage<16,16,4, 35, 256,8, 4, 8, true, true, true, 19, true>(
      binb, buf1, A.offt[0], A.mc[0], tid);
  __syncthreads();
  // ---- conv2: buf1 -> buf2 ----
  for (int i = tid; i < 14080; i += 1024) buf2[i] = 0.f;
  __syncthreads();
  conv_stage<8,8,3, 19, 64,6, 16, 8, true, true, true, 11, true>(
      buf1, buf2, A.offt[1], A.mc[1], tid);
  __syncthreads();
  // ---- conv3: buf2 -> buf3 (unswizzled output; conv4 reads are random-ch) ----
  for (int i = tid; i < 18432; i += 1024) buf3[i] = 0.f;
  __syncthreads();
  conv_stage<4,4,2, 11, 16,4, 64, 8, false, true, true, 6, false>(
      buf2, buf3, A.offt[2], A.mc[2], tid);
  __syncthreads();
  // ---- conv4: buf3 -> h4 (flat, no halo) ----
  conv_stage<2,2,1, 6, 4,2, 256, 4, false, false, false, 1, false>(
      buf3, h4, A.offt[3], A.mc[3], tid);
  __syncthreads();

  // ---- logic1: h4(f32) -> g1h(f16), 40960 rows ----
  {
    const v4i* a4 = (const v4i*)A.la[0];
    const v4i* b4 = (const v4i*)A.lb[0];
    const v4f* w4 = (const v4f*)A.mlw[0];
    #pragma unroll 2
    for (int g = 0; g < 10; ++g) {
      int q = tid + 1024 * g;
      v4i ai = a4[q], bi = b4[q];
      #pragma unroll
      for (int i = 0; i < 4; ++i) {
        v4f w = w4[4 * q + i];
        float a = h4[ai[i]], bb = h4[bi[i]];
        g1h[4 * q + i] = __float2half(fmaf(w.w, a * bb, fmaf(w.z, bb, fmaf(w.y, a, w.x))));
      }
    }
  }
  __syncthreads();
  // ---- logic2: g1h -> g2h, 20480 rows ----
  {
    const v4i* a4 = (const v4i*)A.la[1];
    const v4i* b4 = (const v4i*)A.lb[1];
    const v4f* w4 = (const v4f*)A.mlw[1];
    #pragma unroll 2
    for (int g = 0; g < 5; ++g) {
      int q = tid + 1024 * g;
      v4i ai = a4[q], bi = b4[q];
      #pragma unroll
      for (int i = 0; i < 4; ++i) {
        v4f w = w4[4 * q + i];
        float a = __half2float(g1h[ai[i]]), bb = __half2float(g1h[bi[i]]);
        g2h[4 * q + i] = __float2half(fmaf(w.w, a * bb, fmaf(w.z, bb, fmaf(w.y, a, w.x))));
      }
    }
  }
  __syncthreads();
  // ---- logic3 + group-sum: g2h -> per-class sums ----
  // q in [0,2560); j = 4q; 64 consecutive q per wave lie in one class
  // (256 q per class) -> wave shuffle-reduce, lane0 does one LDS atomic.
  {
    const v4i* a4 = (const v4i*)A.la[2];
    const v4i* b4 = (const v4i*)A.lb[2];
    const v4f* w4 = (const v4f*)A.mlw[2];
    int lane = tid & 63;
    #pragma unroll
    for (int g = 0; g < 3; ++g) {
      int q = tid + 1024 * g;
      if (q < 2560) {                       // whole waves uniform
        v4i ai = a4[q], bi = b4[q];
        float s = 0.f;
        #pragma unroll
        for (int i = 0; i < 4; ++i) {
          v4f w = w4[4 * q + i];
          float a = __half2float(g2h[ai[i]]), bb = __half2float(g2h[bi[i]]);
          s += fmaf(w.w, a * bb, fmaf(w.z, bb, fmaf(w.y, a, w.x)));
        }
        #pragma unroll
        for (int m = 1; m < 64; m <<= 1) s += __shfl_xor(s, m);
        if (lane == 0) atomicAdd(&lsum[q >> 8], s);
      }
    }
  }
  __syncthreads();
  if (tid < 10) A.out[b * 10 + tid] = lsum[tid] * 0.01f;
}

extern "C" void kernel_launch(void* const* d_in, const int* in_sizes, int n_in,
                              void* d_out, int out_size, void* d_ws, size_t ws_size,
                              hipStream_t stream) {
  const float* x   = (const float*)d_in[0];
  const int*   c1i = (const int*)d_in[1];
  const float* c1w = (const float*)d_in[2];
  const int*   c2i = (const int*)d_in[3];
  const float* c2w = (const float*)d_in[4];
  const int*   c3i = (const int*)d_in[5];
  const float* c3w = (const float*)d_in[6];
  const int*   c4i = (const int*)d_in[7];
  const float* c4w = (const float*)d_in[8];
  const int*   l1a = (const int*)d_in[9];
  const int*   l1b = (const int*)d_in[10];
  const float* l1w = (const float*)d_in[11];
  const int*   l2a = (const int*)d_in[12];
  const int*   l2b = (const int*)d_in[13];
  const float* l2w = (const float*)d_in[14];
  const int*   l3a = (const int*)d_in[15];
  const int*   l3b = (const int*)d_in[16];
  const float* l3w = (const float*)d_in[17];

  float* ws = (float*)d_ws;
  float* mc1 = ws;               // 224*4
  float* mc2 = mc1 + 896;        // 896*4
  float* mc3 = mc2 + 3584;       // 3584*4
  float* mc4 = mc3 + 14336;      // 7168*4
  float* ml1 = mc4 + 28672;      // 40960*4
  float* ml2 = ml1 + 163840;     // 20480*4
  float* ml3 = ml2 + 81920;      // 10240*4
  int* off1 = (int*)(ml3 + 40960);   // 32*8
  int* off2 = off1 + 256;            // 128*8
  int* off3 = off2 + 1024;           // 512*8
  int* off4 = off3 + 4096;           // 1024*8

  PrepArgs P;
  P.logits[0] = c1w; P.outm[0] = mc1;
  P.logits[1] = c2w; P.outm[1] = mc2;
  P.logits[2] = c3w; P.outm[2] = mc3;
  P.logits[3] = c4w; P.outm[3] = mc4;
  P.logits[4] = l1w; P.outm[4] = ml1;
  P.logits[5] = l2w; P.outm[5] = ml2;
  P.logits[6] = l3w; P.outm[6] = ml3;
  P.cidx[0] = c1i; P.offt[0] = off1;
  P.cidx[1] = c2i; P.offt[1] = off2;
  P.cidx[2] = c3i; P.offt[2] = off3;
  P.cidx[3] = c4i; P.offt[3] = off4;
  prep_k<<<333, 256, 0, stream>>>(P);

  MegaArgs M;
  M.x = x;
  M.mc[0] = mc1; M.mc[1] = mc2; M.mc[2] = mc3; M.mc[3] = mc4;
  M.offt[0] = off1; M.offt[1] = off2; M.offt[2] = off3; M.offt[3] = off4;
  M.la[0] = l1a; M.lb[0] = l1b; M.mlw[0] = ml1;
  M.la[1] = l2a; M.lb[1] = l2b; M.mlw[1] = ml2;
  M.la[2] = l3a; M.lb[2] = l3b; M.mlw[2] = ml3;
  M.out = (float*)d_out;

  static bool attr_set = false;
  if (!attr_set) {
    hipFuncSetAttribute((const void*)mega_k,
                        hipFuncAttributeMaxDynamicSharedMemorySize, 139328);
    attr_set = true;
  }
  mega_k<<<128, 1024, 139328, stream>>>(M);
}

// Round 6
// 155.507 us; speedup vs baseline: 1.0360x; 1.0123x over previous
//
#include <hip/hip_runtime.h>
#include <hip/hip_fp16.h>

typedef float v2f __attribute__((ext_vector_type(2)));
typedef float v4f __attribute__((ext_vector_type(4)));
typedef int   v4i __attribute__((ext_vector_type(4)));

__device__ __constant__ float GC[16][4] = {
  {0,0,0,0},{0,0,0,1},{0,1,0,-1},{0,1,0,0},
  {0,0,1,-1},{0,0,1,0},{0,1,1,-2},{0,1,1,-1},
  {1,-1,-1,1},{1,-1,-1,2},{1,0,-1,0},{1,0,-1,1},
  {1,-1,0,0},{1,-1,0,1},{1,0,0,-1},{1,0,0,0}};

// ---- packed fp32 helpers (V_PK_FMA/MUL exist on gfx950) ----
__device__ __forceinline__ v2f pk_mul(v2f a, v2f b) {
  v2f d;
  asm("v_pk_mul_f32 %0, %1, %2" : "=v"(d) : "v"(a), "v"(b));
  return d;
}
// r = w0 + w1*a + w2*b + w3*(a*b), per half; w01=(w0,w1) pair, w23=(w2,w3).
__device__ __forceinline__ v2f gate2pk(v2f a, v2f b, v2f w01, v2f w23) {
  v2f t = pk_mul(a, b);
  v2f d;
  asm("v_pk_fma_f32 %0, %1, %2, %2 op_sel:[0,1,0] op_sel_hi:[1,1,0]"
      : "=v"(d) : "v"(a), "v"(w01));
  asm("v_pk_fma_f32 %0, %1, %2, %0 op_sel:[0,0,0] op_sel_hi:[1,0,1]"
      : "+v"(d) : "v"(b), "v"(w23));
  asm("v_pk_fma_f32 %0, %1, %2, %0 op_sel:[0,1,0] op_sel_hi:[1,1,1]"
      : "+v"(d) : "v"(t), "v"(w23));
  return d;
}

__device__ __forceinline__ void mix_one(const float* lp, float* op) {
  // logits are 0.01*N(0,1) (+5 on slot 3): exp() safe without max-shift
  float e[16];
  float s = 0.f;
  #pragma unroll
  for (int i = 0; i < 16; ++i) { e[i] = __expf(lp[i]); s += e[i]; }
  float inv = 1.0f / s;
  float w0 = 0.f, w1 = 0.f, w2 = 0.f, w3 = 0.f;
  #pragma unroll
  for (int i = 0; i < 16; ++i) {
    float p = e[i] * inv;
    w0 = fmaf(p, GC[i][0], w0);
    w1 = fmaf(p, GC[i][1], w1);
    w2 = fmaf(p, GC[i][2], w2);
    w3 = fmaf(p, GC[i][3], w3);
  }
  op[0] = w0; op[1] = w1; op[2] = w2; op[3] = w3;
}

struct PrepArgs {
  const float* logits[7];
  float* outm[7];
  const int* cidx[4];
  int* offt[4];
};

// gid 0..83551: weight softmax-mix -> 4 coefs/row.
// gid 83552..85247: decode leaf indices into LDS element offsets relative to
// zero-halo'd buffers. Row strides / channel strides are chosen per-layer for
// bank-conflict freedom:
//  L0 binb: rows 35, CS 1190, parity swizzle
//  L1 buf1: rows 19, CS 342,  parity swizzle
//  L2 buf2: rows 12, CS 120,  parity swizzle (S=24 tiles banks)
//  L3 buf3: rows 6,  CS 37 (odd -> random channels hash all 32 banks)
__global__ __launch_bounds__(256) void prep_k(PrepArgs A) {
  int gid = blockIdx.x * 256 + threadIdx.x;
  if (gid < 83552) {
    const int n[7] = {224, 896, 3584, 7168, 40960, 20480, 10240};
    int g = gid, seg = 0;
    while (seg < 6 && g >= n[seg]) { g -= n[seg]; ++seg; }
    mix_one(A.logits[seg] + (size_t)g * 16, A.outm[seg] + (size_t)g * 4);
  } else if (gid < 85248) {
    int r = gid - 83552;
    int L, rr;
    if (r < 32)       { L = 0; rr = r;       }
    else if (r < 160) { L = 1; rr = r - 32;  }
    else if (r < 672) { L = 2; rr = r - 160; }
    else              { L = 3; rr = r - 672; }
    const int W2Pt[4] = {35, 19, 12, 6};
    const int CSt[4]  = {1190, 342, 120, 37};
    const int swzt[4] = {1, 1, 1, 0};
    int W2P = W2Pt[L], CS = CSt[L], swz = swzt[L];
    const int* ci = A.cidx[L] + rr * 8;
    int* oo = A.offt[L] + rr * 8;
    #pragma unroll
    for (int l = 0; l < 8; ++l) {
      int idx = ci[l];
      int c  = idx / 9;
      int k  = idx - 9 * c;
      int di = k / 3 - 1;
      int dj = k - 3 * (k / 3) - 1;
      int yl = 1 + di;                      // 0..2
      int off = c * CS + yl * W2P + 1 + dj;
      if (swz)
        off |= (((yl >> 1) & 1) << 28) | ((((yl + 1) >> 1) & 1) << 29);
      oo[l] = off;
    }
  }
}

struct MegaArgs {
  const float* x;
  const float* mc[4];    // mixed conv weights (OC x 28)
  const int*   offt[4];  // decoded leaf offsets (OC x 8)
  const int*   la[3];
  const int*   lb[3];
  const float* mlw[3];   // mixed logic weights (N x 4)
  float* out;
};

extern __shared__ char S[];

// One conv+or_pool layer, input/output in LDS (zero halo -> no bounds checks,
// row swizzle / stride choice -> bank-conflict-free stride-2 lane access).
template<int OH, int OW, int LOGOW, int IW2P, int PIXCNT, int LOGPIX,
         int NCH, int ITERS, bool UNI, bool RSWZ, bool OHALO, int OW2P,
         int OCS, bool OSWZ>
__device__ __forceinline__ void conv_stage(
    const float* in, float* outb,
    const int* __restrict__ offt, const float* __restrict__ mtab, int tid) {
  int pix = tid & (PIXCNT - 1);
  int ch0 = tid >> LOGPIX;
  int pw  = pix & (OW - 1);
  int ph  = pix >> LOGOW;
  int pixbase = 2 * ph * IW2P + 2 * pw;
  int ph1 = ph & 1;
  #pragma unroll 4
  for (int it = 0; it < ITERS; ++it) {
    int ch = ch0 + NCH * it;
    if (UNI) ch = __builtin_amdgcn_readfirstlane(ch);
    const int* ot = offt + ch * 8;
    const float* mt = mtab + ch * 28;
    v4f g0 = *(const v4f*)(mt +  0);
    v4f g1 = *(const v4f*)(mt +  4);
    v4f g2 = *(const v4f*)(mt +  8);
    v4f g3 = *(const v4f*)(mt + 12);
    v4f g4 = *(const v4f*)(mt + 16);
    v4f g5 = *(const v4f*)(mt + 20);
    v4f g6 = *(const v4f*)(mt + 24);
    v2f v01[8], v23[8];
    #pragma unroll
    for (int l = 0; l < 8; ++l) {
      int e = ot[l];
      int at, ab;
      if (RSWZ) {
        int off = e & 0x0FFFFFFF;
        at = off + pixbase + ((ph1 ^ (e >> 28)) & 1);
        ab = off + pixbase + IW2P + ((ph1 ^ (e >> 29)) & 1);
      } else {
        at = e + pixbase;
        ab = at + IW2P;
      }
      v2f t0; t0.x = in[at]; t0.y = in[at + 1];
      v2f t1; t1.x = in[ab]; t1.y = in[ab + 1];
      v01[l] = t0; v23[l] = t1;
    }
    v2f u0 = gate2pk(v01[0], v01[1], g0.xy, g0.zw);
    v2f u1 = gate2pk(v01[2], v01[3], g1.xy, g1.zw);
    v2f u2 = gate2pk(v01[4], v01[5], g2.xy, g2.zw);
    v2f u3 = gate2pk(v01[6], v01[7], g3.xy, g3.zw);
    v2f s0 = gate2pk(u0, u1, g4.xy, g4.zw);
    v2f s1 = gate2pk(u2, u3, g5.xy, g5.zw);
    v2f r0 = gate2pk(s0, s1, g6.xy, g6.zw);
    u0 = gate2pk(v23[0], v23[1], g0.xy, g0.zw);
    u1 = gate2pk(v23[2], v23[3], g1.xy, g1.zw);
    u2 = gate2pk(v23[4], v23[5], g2.xy, g2.zw);
    u3 = gate2pk(v23[6], v23[7], g3.xy, g3.zw);
    s0 = gate2pk(u0, u1, g4.xy, g4.zw);
    s1 = gate2pk(u2, u3, g5.xy, g5.zw);
    v2f r1 = gate2pk(s0, s1, g6.xy, g6.zw);
    float res = fmaxf(fmaxf(r0.x, r0.y), fmaxf(r1.x, r1.y));
    if (OHALO) {
      int oy = 1 + ph;
      int widx = ch * OCS + oy * OW2P + 1 + pw;
      if (OSWZ) widx += (oy >> 1) & 1;
      outb[widx] = res;
    } else {
      outb[ch * (OH * OW) + pix] = res;
    }
  }
}

// LDS layout (bytes), two ping-pong regions A@0 (61440) and B@61440 (75776):
//  binb [9][34][35]+pad f32 @ A      (42848)
//  buf1 [32][18][19] f32    @ B      (43776)
//  buf2 [128][10][12] f32   @ A      (61440)
//  buf3 [512 x 37] f32      @ B      (75776)  ends 137216
//  h4   [4096] f32          @ 0      (16384)
//  g1h  [40960] f16         @ 16384  (81920)  ends 98304
//  g2h  [20480] f16         @ 98304  (40960)  ends 139264
//  lsum [10] f32            @ 139264
__global__ __launch_bounds__(1024) void mega_k(MegaArgs A) {
  int tid = threadIdx.x;
  int b = blockIdx.x;
  float* binb = (float*)(S);
  float* buf1 = (float*)(S + 61440);
  float* buf2 = (float*)(S);
  float* buf3 = (float*)(S + 61440);
  float* h4   = (float*)(S);
  __half* g1h = (__half*)(S + 16384);
  __half* g2h = (__half*)(S + 98304);
  float* lsum = (float*)(S + 139264);
  const v4f z4 = {0.f, 0.f, 0.f, 0.f};

  // ---- binarize into zero-halo'd, row-swizzled binb ----
  for (int i = 4 * tid; i < 10712; i += 4096) *(v4f*)(binb + i) = z4;
  if (tid < 10) lsum[tid] = 0.f;
  __syncthreads();
  const float* xb = A.x + (size_t)b * 3072;
  #pragma unroll
  for (int i = 0; i < 3; ++i) {
    int idx = tid + 1024 * i;
    float v = xb[idx];
    int rgb = idx >> 10;
    int rem = idx & 1023;
    int y = rem >> 5, xx = rem & 31;
    int oy = 1 + y;
    int base = oy * 35 + 1 + xx + ((oy >> 1) & 1);
    binb[(0 + rgb) * 1190 + base] = v > 0.25f ? 1.f : 0.f;
    binb[(3 + rgb) * 1190 + base] = v > 0.50f ? 1.f : 0.f;
    binb[(6 + rgb) * 1190 + base] = v > 0.75f ? 1.f : 0.f;
  }
  __syncthreads();

  // ---- conv1: binb -> buf1 ----
  for (int i = 4 * tid; i < 10944; i += 4096) *(v4f*)(buf1 + i) = z4;
  __syncthreads();
  conv_stage<16,16,4, 35, 256,8, 4, 8, true, true, true, 19, 342, true>(
      binb, buf1, A.offt[0], A.mc[0], tid);
  __syncthreads();
  // ---- conv2: buf1 -> buf2 ----
  for (int i = 4 * tid; i < 15360; i += 4096) *(v4f*)(buf2 + i) = z4;
  __syncthreads();
  conv_stage<8,8,3, 19, 64,6, 16, 8, true, true, true, 12, 120, true>(
      buf1, buf2, A.offt[1], A.mc[1], tid);
  __syncthreads();
  // ---- conv3: buf2 -> buf3 (odd channel stride 37, unswizzled) ----
  for (int i = 4 * tid; i < 18944; i += 4096) *(v4f*)(buf3 + i) = z4;
  __syncthreads();
  conv_stage<4,4,2, 12, 16,4, 64, 8, false, true, true, 6, 37, false>(
      buf2, buf3, A.offt[2], A.mc[2], tid);
  __syncthreads();
  // ---- conv4: buf3 -> h4 (flat, no halo) ----
  conv_stage<2,2,1, 6, 4,2, 256, 4, false, false, false, 1, 4, false>(
      buf3, h4, A.offt[3], A.mc[3], tid);
  __syncthreads();

  // ---- logic1: h4(f32) -> g1h(f16), 40960 rows, packed b64 stores ----
  {
    const v4i* a4 = (const v4i*)A.la[0];
    const v4i* b4 = (const v4i*)A.lb[0];
    const v4f* w4 = (const v4f*)A.mlw[0];
    #pragma unroll 2
    for (int g = 0; g < 10; ++g) {
      int q = tid + 1024 * g;
      v4i ai = a4[q], bi = b4[q];
      float r[4];
      #pragma unroll
      for (int i = 0; i < 4; ++i) {
        v4f w = w4[4 * q + i];
        float a = h4[ai[i]], bb = h4[bi[i]];
        r[i] = fmaf(w.w, a * bb, fmaf(w.z, bb, fmaf(w.y, a, w.x)));
      }
      union { __half2 h[2]; uint2 u; } P;
      P.h[0] = __floats2half2_rn(r[0], r[1]);
      P.h[1] = __floats2half2_rn(r[2], r[3]);
      *(uint2*)(g1h + 4 * q) = P.u;
    }
  }
  __syncthreads();
  // ---- logic2: g1h -> g2h, 20480 rows ----
  {
    const v4i* a4 = (const v4i*)A.la[1];
    const v4i* b4 = (const v4i*)A.lb[1];
    const v4f* w4 = (const v4f*)A.mlw[1];
    #pragma unroll 2
    for (int g = 0; g < 5; ++g) {
      int q = tid + 1024 * g;
      v4i ai = a4[q], bi = b4[q];
      float r[4];
      #pragma unroll
      for (int i = 0; i < 4; ++i) {
        v4f w = w4[4 * q + i];
        float a = __half2float(g1h[ai[i]]), bb = __half2float(g1h[bi[i]]);
        r[i] = fmaf(w.w, a * bb, fmaf(w.z, bb, fmaf(w.y, a, w.x)));
      }
      union { __half2 h[2]; uint2 u; } P;
      P.h[0] = __floats2half2_rn(r[0], r[1]);
      P.h[1] = __floats2half2_rn(r[2], r[3]);
      *(uint2*)(g2h + 4 * q) = P.u;
    }
  }
  __syncthreads();
  // ---- logic3 + group-sum: g2h -> per-class sums ----
  // q in [0,2560); j = 4q; 64 consecutive q per wave lie in one class
  // (256 q per class) -> wave shuffle-reduce, lane0 does one LDS atomic.
  {
    const v4i* a4 = (const v4i*)A.la[2];
    const v4i* b4 = (const v4i*)A.lb[2];
    const v4f* w4 = (const v4f*)A.mlw[2];
    int lane = tid & 63;
    #pragma unroll
    for (int g = 0; g < 3; ++g) {
      int q = tid + 1024 * g;
      if (q < 2560) {                       // whole waves uniform
        v4i ai = a4[q], bi = b4[q];
        float s = 0.f;
        #pragma unroll
        for (int i = 0; i < 4; ++i) {
          v4f w = w4[4 * q + i];
          float a = __half2float(g2h[ai[i]]), bb = __half2float(g2h[bi[i]]);
          s += fmaf(w.w, a * bb, fmaf(w.z, bb, fmaf(w.y, a, w.x)));
        }
        #pragma unroll
        for (int m = 1; m < 64; m <<= 1) s += __shfl_xor(s, m);
        if (lane == 0) atomicAdd(&lsum[q >> 8], s);
      }
    }
  }
  __syncthreads();
  if (tid < 10) A.out[b * 10 + tid] = lsum[tid] * 0.01f;
}

extern "C" void kernel_launch(void* const* d_in, const int* in_sizes, int n_in,
                              void* d_out, int out_size, void* d_ws, size_t ws_size,
                              hipStream_t stream) {
  const float* x   = (const float*)d_in[0];
  const int*   c1i = (const int*)d_in[1];
  const float* c1w = (const float*)d_in[2];
  const int*   c2i = (const int*)d_in[3];
  const float* c2w = (const float*)d_in[4];
  const int*   c3i = (const int*)d_in[5];
  const float* c3w = (const float*)d_in[6];
  const int*   c4i = (const int*)d_in[7];
  const float* c4w = (const float*)d_in[8];
  const int*   l1a = (const int*)d_in[9];
  const int*   l1b = (const int*)d_in[10];
  const float* l1w = (const float*)d_in[11];
  const int*   l2a = (const int*)d_in[12];
  const int*   l2b = (const int*)d_in[13];
  const float* l2w = (const float*)d_in[14];
  const int*   l3a = (const int*)d_in[15];
  const int*   l3b = (const int*)d_in[16];
  const float* l3w = (const float*)d_in[17];

  float* ws = (float*)d_ws;
  float* mc1 = ws;               // 224*4
  float* mc2 = mc1 + 896;        // 896*4
  float* mc3 = mc2 + 3584;       // 3584*4
  float* mc4 = mc3 + 14336;      // 7168*4
  float* ml1 = mc4 + 28672;      // 40960*4
  float* ml2 = ml1 + 163840;     // 20480*4
  float* ml3 = ml2 + 81920;      // 10240*4
  int* off1 = (int*)(ml3 + 40960);   // 32*8
  int* off2 = off1 + 256;            // 128*8
  int* off3 = off2 + 1024;           // 512*8
  int* off4 = off3 + 4096;           // 1024*8

  PrepArgs P;
  P.logits[0] = c1w; P.outm[0] = mc1;
  P.logits[1] = c2w; P.outm[1] = mc2;
  P.logits[2] = c3w; P.outm[2] = mc3;
  P.logits[3] = c4w; P.outm[3] = mc4;
  P.logits[4] = l1w; P.outm[4] = ml1;
  P.logits[5] = l2w; P.outm[5] = ml2;
  P.logits[6] = l3w; P.outm[6] = ml3;
  P.cidx[0] = c1i; P.offt[0] = off1;
  P.cidx[1] = c2i; P.offt[1] = off2;
  P.cidx[2] = c3i; P.offt[2] = off3;
  P.cidx[3] = c4i; P.offt[3] = off4;
  prep_k<<<333, 256, 0, stream>>>(P);

  MegaArgs M;
  M.x = x;
  M.mc[0] = mc1; M.mc[1] = mc2; M.mc[2] = mc3; M.mc[3] = mc4;
  M.offt[0] = off1; M.offt[1] = off2; M.offt[2] = off3; M.offt[3] = off4;
  M.la[0] = l1a; M.lb[0] = l1b; M.mlw[0] = ml1;
  M.la[1] = l2a; M.lb[1] = l2b; M.mlw[1] = ml2;
  M.la[2] = l3a; M.lb[2] = l3b; M.mlw[2] = ml3;
  M.out = (float*)d_out;

  static bool attr_set = false;
  if (!attr_set) {
    hipFuncSetAttribute((const void*)mega_k,
                        hipFuncAttributeMaxDynamicSharedMemorySize, 139328);
    attr_set = true;
  }
  mega_k<<<128, 1024, 139328, stream>>>(M);
}